// Round 7
// baseline (511.052 us; speedup 1.0000x reference)
//
#include <hip/hip_runtime.h>
#include <hip/hip_bf16.h>

// LGCN_Encoder via Gram-matrix collapse.
//   G = V^T V (512x512, layer-invariant), c0 = V^T ego0
//   c_{k+1} = G (f_k ⊙ c_k)  [tiny]
//   out = (ego0 + V (w1+w2+w3))/4,  w_k = f_{k-1} ⊙ c_{k-1}
//
// R7 (from R6=486.8us; R6 gram levers both hurt -> reverted; expand pure-h
// kept, saved ~40us):
//  gram is staging-VALU-bound (~200 VALU insts/step vs 48 MFMA; VALUBusy 35
//  vs MfmaUtil 21). Fix: PRE-SPLIT V once into MFMA-blob bf16 h/l arrays
//  (presplit_kernel, clone of proven init writer); gram staging becomes a
//  pure 16B-load + identity ds_write copy (the proven isC0 path generalized)
//  -> no split_pair, no bounds checks, no f32 addr math in the loop.
//  Workspace risk: fast path needs ~206MB (unproven); launcher falls back to
//  the R4-proven split-in-kernel gram if ws_size is too small. Both compiled;
//  distinct names so rocprof shows which ran.

#define N_USERS 29858
#define N_TOTAL 70839
#define DQ 64
#define FD 512
#define NPAD 71168   // 139*512

typedef __attribute__((ext_vector_type(8))) short short8;
typedef __attribute__((ext_vector_type(4))) float f32x4;
typedef unsigned int u32;
typedef unsigned short u16;

static __device__ __forceinline__ u32 f32u(float x){union{float f;u32 u;}a;a.f=x;return a.u;}
static __device__ __forceinline__ float uf32(u32 u){union{u32 u;float f;}a;a.u=u;return a.f;}
// pack high halves: (hi16(x1)<<16) | hi16(x0)
static __device__ __forceinline__ u32 pack_h(u32 x0, u32 x1){
  return __builtin_amdgcn_perm(x1, x0, 0x07060302u);
}
// trunc split of two f32 into bf16 h-pair and l-pair dwords
static __device__ __forceinline__ void split_pair(u32 x0, u32 x1, u32& hp, u32& lp) {
  hp = pack_h(x0, x1);
  u32 l0 = f32u(uf32(x0) - uf32(x0 & 0xFFFF0000u));
  u32 l1 = f32u(uf32(x1) - uf32(x1 & 0xFFFF0000u));
  lp = pack_h(l0, l1);
}
union U8x { u32 u[4]; short8 s; };

static __device__ __forceinline__ u16 bf16_rne(float x) {
  u32 u = f32u(x);
  return (u16)((u + 0x7FFFu + ((u >> 16) & 1u)) >> 16);
}
static __device__ __forceinline__ void split2(float x, u16& h, u16& l) {
  h = bf16_rne(x);
  l = bf16_rne(x - uf32(((u32)h) << 16));
}

static __device__ __forceinline__ void load_lds16(const float* g, float* l) {
  __builtin_amdgcn_global_load_lds(
      (const __attribute__((address_space(1))) u32*)(g),
      (__attribute__((address_space(3))) u32*)(l), 16, 0, 0);
}

// Blob layout (verified via egoTb / R3-Output0 hardware evidence):
// tile T = (n>>5)*8 + (f>>6); within tile, slot s = (f&63 pieces):
//   s = (f'&15) + ((f'>>4)&3)*64 + ((n'>>3)&3)*16, f'=f&63, n'=n&31.
// Slot s holds 8 bf16, n ascending. Fragment (ct,m16,quad) reads slot
// m16 + ct*64 + quad*16 -> B[k=quad*8+j][col=ct*16+m16]; A-fragments use
// the same slot math (mt,wv in place of ct): layouts coincide.

// ---------------------------------------------------------------- init
// out = concat(user,item) (for expand's RMW); egoTb = ego0 pre-split blobs.
__global__ __launch_bounds__(256) void init_kernel(
    const float* __restrict__ u, const float* __restrict__ it,
    float* __restrict__ out, u16* __restrict__ egoTb) {
  __shared__ float tile[64][65];
  const int n0 = blockIdx.x * 64;
  const int t = threadIdx.x;
  const int r = t >> 2, cbase = (t & 3) * 16;
  {
    int n = n0 + r;
    if (n < N_TOTAL) {
      const float* src = (n < N_USERS) ? (u + (size_t)n * DQ)
                                       : (it + (size_t)(n - N_USERS) * DQ);
#pragma unroll
      for (int q = 0; q < 4; ++q) {
        f32x4 val = *(const f32x4*)(src + cbase + q * 4);
        *(f32x4*)(out + (size_t)n * DQ + cbase + q * 4) = val;
        tile[r][cbase + q * 4 + 0] = val[0];
        tile[r][cbase + q * 4 + 1] = val[1];
        tile[r][cbase + q * 4 + 2] = val[2];
        tile[r][cbase + q * 4 + 3] = val[3];
      }
    } else {
#pragma unroll
      for (int q = 0; q < 4; ++q)
#pragma unroll
        for (int e = 0; e < 4; ++e) tile[r][cbase + q * 4 + e] = 0.f;
    }
  }
  __syncthreads();
  const int d = (t & 15) | ((t >> 6) << 4);
  const int nb = (t >> 4) & 3;
#pragma unroll
  for (int sl = 0; sl < 2; ++sl) {
    U8x H, L;
#pragma unroll
    for (int j = 0; j < 4; ++j) {
      u16 h0, l0, h1, l1;
      split2(tile[sl * 32 + nb * 8 + 2 * j][d], h0, l0);
      split2(tile[sl * 32 + nb * 8 + 2 * j + 1][d], h1, l1);
      H.u[j] = (u32)h0 | ((u32)h1 << 16);
      L.u[j] = (u32)l0 | ((u32)l1 << 16);
    }
    size_t base = (size_t)(blockIdx.x * 2 + sl) * 4096;  // u16 units
    *(short8*)(egoTb + base + (size_t)t * 8) = H.s;
    *(short8*)(egoTb + base + 2048 + (size_t)t * 8) = L.s;
  }
}

// ---------------------------------------------------------------- presplit
// V -> vbh/vbl blobs (trunc split, matching gram_split numerics exactly).
// Per block: 64 rows x 512 f, 8 sub-tiles via the proven LDS-transpose.
__global__ __launch_bounds__(256) void presplit_kernel(
    const float* __restrict__ v, u16* __restrict__ vbh, u16* __restrict__ vbl) {
  __shared__ float tile[64][65];
  const int n0 = blockIdx.x * 64;
  const int t = threadIdx.x;
  const int r = t >> 2, cbase = (t & 3) * 16;
  const int d = (t & 15) | ((t >> 6) << 4);
  const int nb = (t >> 4) & 3;
  for (int fo = 0; fo < FD; fo += 64) {
    __syncthreads();  // previous iter's blob readers done with tile
    {
      int n = n0 + r;
      if (n < N_TOTAL) {
        const float* src = v + (size_t)n * FD + fo;
#pragma unroll
        for (int q = 0; q < 4; ++q) {
          f32x4 val = *(const f32x4*)(src + cbase + q * 4);
          tile[r][cbase + q * 4 + 0] = val[0];
          tile[r][cbase + q * 4 + 1] = val[1];
          tile[r][cbase + q * 4 + 2] = val[2];
          tile[r][cbase + q * 4 + 3] = val[3];
        }
      } else {
#pragma unroll
        for (int q = 0; q < 4; ++q)
#pragma unroll
          for (int e = 0; e < 4; ++e) tile[r][cbase + q * 4 + e] = 0.f;
      }
    }
    __syncthreads();
#pragma unroll
    for (int sl = 0; sl < 2; ++sl) {
      U8x H, L;
#pragma unroll
      for (int j = 0; j < 4; ++j) {
        u32 x0 = f32u(tile[sl * 32 + nb * 8 + 2 * j][d]);
        u32 x1 = f32u(tile[sl * 32 + nb * 8 + 2 * j + 1][d]);
        split_pair(x0, x1, H.u[j], L.u[j]);
      }
      size_t T = (size_t)((n0 >> 5) + sl) * 8 + (fo >> 6);
      *(short8*)(vbh + T * 2048 + (size_t)t * 8) = H.s;
      *(short8*)(vbl + T * 2048 + (size_t)t * 8) = L.s;
    }
  }
}

// ---------------------------------------------------------------- gram_fast
// Staging = pure 16B-blob copy (no split, no bounds). Job decode, barrier
// structure, fragment reads, MFMA loop, epilogue: verbatim the proven gram.
__global__ __launch_bounds__(256, 2) void gram_fast_kernel(
    const u16* __restrict__ vbh, const u16* __restrict__ vbl,
    const u16* __restrict__ egoTb, float* __restrict__ parts, int chunk) {
  __shared__ short8 HAh[1024];   // 256 f x 4 n-blk, 16 KB
  __shared__ short8 HAl[1024];
  __shared__ short8 HBh[256];    // 64 cols x 4 n-blk, 4 KB
  __shared__ short8 HBl[256];

  const int job = blockIdx.x;
  const int n0c = blockIdx.y * chunk;
  const int nend = min(n0c + chunk, NPAD);
  const bool isC0 = (job >= 12);
  const int itile = isC0 ? (job - 12) : (job < 8 ? 0 : 1);
  const int fA = itile * 256;
  const int jcol = isC0 ? 0 : (job < 8 ? job : job - 4);
  const int colbase = jcol * 64;
  const bool reuseB = !isC0 && (colbase >= fA) && (colbase + 64 <= fA + 256);
  const bool stageB = !isC0 && !reuseB;
  const int cb0q = reuseB ? ((colbase - fA) >> 6) : 0;

  const int t = threadIdx.x;
  const int lane = t & 63, wv = t >> 6;
  const int m16 = lane & 15, quad = lane >> 4;
  const int ftA = fA >> 6;

  f32x4 acc[4][4];
#pragma unroll
  for (int a = 0; a < 4; ++a)
#pragma unroll
    for (int b = 0; b < 4; ++b) acc[a][b] = (f32x4){0.f, 0.f, 0.f, 0.f};

  short8 xAh[4], xAl[4], xBh, xBl;

  auto issue = [&](int n0) {
    size_t Tb = (size_t)(n0 >> 5) * 8;
    if (isC0) {
      xBh = *(const short8*)(egoTb + (size_t)(n0 >> 5) * 4096 + (size_t)t * 8);
      xBl = *(const short8*)(egoTb + (size_t)(n0 >> 5) * 4096 + 2048 + (size_t)t * 8);
    } else if (stageB) {
      size_t base = (Tb + (colbase >> 6)) * 2048 + (size_t)t * 8;
      xBh = *(const short8*)(vbh + base);
      xBl = *(const short8*)(vbl + base);
    }
#pragma unroll
    for (int seg = 0; seg < 4; ++seg) {
      size_t base = (Tb + ftA + seg) * 2048 + (size_t)t * 8;
      xAh[seg] = *(const short8*)(vbh + base);
      xAl[seg] = *(const short8*)(vbl + base);
    }
  };

  issue(n0c);

  for (int n0 = n0c; n0 < nend; n0 += 32) {
    asm volatile("s_barrier" ::: "memory");  // prev step's LDS reads done

#pragma unroll
    for (int seg = 0; seg < 4; ++seg) {
      HAh[seg * 256 + t] = xAh[seg];
      HAl[seg * 256 + t] = xAl[seg];
    }
    if (stageB || isC0) {
      HBh[t] = xBh;
      HBl[t] = xBl;
    }

    // prefetch next step's blobs: stay in flight across barrier + MFMAs
    if (n0 + 32 < nend) issue(n0 + 32);

    asm volatile("s_waitcnt lgkmcnt(0)" ::: "memory");  // ds_writes visible
    asm volatile("s_barrier" ::: "memory");             // NOT vmcnt-drained

    short8 ah[4], al[4];
#pragma unroll
    for (int mt = 0; mt < 4; ++mt) {
      int u = m16 + mt * 64 + wv * 256 + quad * 16;
      ah[mt] = HAh[u];
      al[mt] = HAl[u];
    }
#pragma unroll
    for (int ct = 0; ct < 4; ++ct) {
      short8 bh, bl;
      if (reuseB) {
        int u = m16 + ct * 64 + cb0q * 256 + quad * 16;
        bh = HAh[u]; bl = HAl[u];
      } else {
        int u = m16 + ct * 64 + quad * 16;
        bh = HBh[u]; bl = HBl[u];
      }
#pragma unroll
      for (int mt = 0; mt < 4; ++mt) {
        acc[mt][ct] = __builtin_amdgcn_mfma_f32_16x16x32_bf16(ah[mt], bh, acc[mt][ct], 0, 0, 0);
        acc[mt][ct] = __builtin_amdgcn_mfma_f32_16x16x32_bf16(ah[mt], bl, acc[mt][ct], 0, 0, 0);
        acc[mt][ct] = __builtin_amdgcn_mfma_f32_16x16x32_bf16(al[mt], bh, acc[mt][ct], 0, 0, 0);
      }
    }
  }

  float* pb = parts + (size_t)blockIdx.y * (512 * 576);
  const int cb = isC0 ? 512 : colbase;
#pragma unroll
  for (int mt = 0; mt < 4; ++mt) {
    int row = fA + wv * 64 + mt * 16 + quad * 4;
#pragma unroll
    for (int ct = 0; ct < 4; ++ct) {
      int col = cb + ct * 16 + m16;
#pragma unroll
      for (int reg = 0; reg < 4; ++reg)
        pb[(size_t)(row + reg) * 576 + col] = acc[mt][ct][reg];
    }
  }
}

// ---------------------------------------------------------------- gram_split
// R4-proven fallback (in-kernel f32 load + split), used when ws_size can't
// hold the vb blobs. Verbatim R4 gram_kernel.
__global__ __launch_bounds__(256, 2) void gram_split_kernel(
    const float* __restrict__ v, const u16* __restrict__ egoTb,
    float* __restrict__ parts, int chunk) {
  __shared__ short8 HAh[1024];
  __shared__ short8 HAl[1024];
  __shared__ short8 HBh[256];
  __shared__ short8 HBl[256];

  const int job = blockIdx.x;
  const int n0c = blockIdx.y * chunk;
  const int nend = min(n0c + chunk, NPAD);
  const bool isC0 = (job >= 12);
  const int itile = isC0 ? (job - 12) : (job < 8 ? 0 : 1);
  const int fA = itile * 256;
  const int jcol = isC0 ? 0 : (job < 8 ? job : job - 4);
  const int colbase = jcol * 64;
  const bool reuseB = !isC0 && (colbase >= fA) && (colbase + 64 <= fA + 256);
  const bool stageB = !isC0 && !reuseB;
  const int cb0q = reuseB ? ((colbase - fA) >> 6) : 0;

  const int t = threadIdx.x;
  const int lane = t & 63, wv = t >> 6;
  const int m16 = lane & 15, quad = lane >> 4;
  const int fl = lane, nq = wv;

  f32x4 acc[4][4];
#pragma unroll
  for (int a = 0; a < 4; ++a)
#pragma unroll
    for (int b = 0; b < 4; ++b) acc[a][b] = (f32x4){0.f, 0.f, 0.f, 0.f};

  u32 xA[4][8];
  u32 xB[8];
  short8 xBh, xBl;

  auto issue = [&](int n0) {
    if (isC0) {
      xBh = *(const short8*)(egoTb + (size_t)(n0 >> 5) * 4096 + (size_t)t * 8);
      xBl = *(const short8*)(egoTb + (size_t)(n0 >> 5) * 4096 + 2048 + (size_t)t * 8);
    }
#pragma unroll
    for (int seg = 0; seg < 4; ++seg)
#pragma unroll
      for (int r = 0; r < 8; ++r) {
        int n = n0 + nq * 8 + r;
        xA[seg][r] = (n < N_TOTAL) ? f32u(v[(size_t)n * FD + fA + seg * 64 + fl]) : 0u;
      }
    if (stageB) {
#pragma unroll
      for (int r = 0; r < 8; ++r) {
        int n = n0 + nq * 8 + r;
        xB[r] = (n < N_TOTAL) ? f32u(v[(size_t)n * FD + colbase + fl]) : 0u;
      }
    }
  };

  issue(n0c);

  for (int n0 = n0c; n0 < nend; n0 += 32) {
    asm volatile("s_barrier" ::: "memory");

    const int uw = (fl & 15) + ((fl >> 4) & 3) * 64 + nq * 16;
#pragma unroll
    for (int seg = 0; seg < 4; ++seg) {
      U8x H, L;
#pragma unroll
      for (int p = 0; p < 4; ++p)
        split_pair(xA[seg][2 * p], xA[seg][2 * p + 1], H.u[p], L.u[p]);
      HAh[uw + seg * 256] = H.s;
      HAl[uw + seg * 256] = L.s;
    }
    if (stageB) {
      U8x H, L;
#pragma unroll
      for (int p = 0; p < 4; ++p)
        split_pair(xB[2 * p], xB[2 * p + 1], H.u[p], L.u[p]);
      HBh[uw] = H.s;
      HBl[uw] = L.s;
    } else if (isC0) {
      HBh[t] = xBh;
      HBl[t] = xBl;
    }

    if (n0 + 32 < nend) issue(n0 + 32);

    asm volatile("s_waitcnt lgkmcnt(0)" ::: "memory");
    asm volatile("s_barrier" ::: "memory");

    short8 ah[4], al[4];
#pragma unroll
    for (int mt = 0; mt < 4; ++mt) {
      int u = m16 + mt * 64 + wv * 256 + quad * 16;
      ah[mt] = HAh[u];
      al[mt] = HAl[u];
    }
#pragma unroll
    for (int ct = 0; ct < 4; ++ct) {
      short8 bh, bl;
      if (reuseB) {
        int u = m16 + ct * 64 + cb0q * 256 + quad * 16;
        bh = HAh[u]; bl = HAl[u];
      } else {
        int u = m16 + ct * 64 + quad * 16;
        bh = HBh[u]; bl = HBl[u];
      }
#pragma unroll
      for (int mt = 0; mt < 4; ++mt) {
        acc[mt][ct] = __builtin_amdgcn_mfma_f32_16x16x32_bf16(ah[mt], bh, acc[mt][ct], 0, 0, 0);
        acc[mt][ct] = __builtin_amdgcn_mfma_f32_16x16x32_bf16(ah[mt], bl, acc[mt][ct], 0, 0, 0);
        acc[mt][ct] = __builtin_amdgcn_mfma_f32_16x16x32_bf16(al[mt], bh, acc[mt][ct], 0, 0, 0);
      }
    }
  }

  float* pb = parts + (size_t)blockIdx.y * (512 * 576);
  const int cb = isC0 ? 512 : colbase;
#pragma unroll
  for (int mt = 0; mt < 4; ++mt) {
    int row = fA + wv * 64 + mt * 16 + quad * 4;
#pragma unroll
    for (int ct = 0; ct < 4; ++ct) {
      int col = cb + ct * 16 + m16;
#pragma unroll
      for (int reg = 0; reg < 4; ++reg)
        pb[(size_t)(row + reg) * 576 + col] = acc[mt][ct][reg];
    }
  }
}

// ---------------------------------------------------------------- finalize
__global__ __launch_bounds__(256) void finalize_kernel(
    const float* __restrict__ parts, int nc,
    float* __restrict__ G, float* __restrict__ c0) {
  int idx = blockIdx.x * 256 + threadIdx.x;  // 512*576
  int r = idx / 576, c = idx % 576;
  float s = 0.f;
  if (c >= 512) {
    for (int p = 0; p < nc; ++p) s += parts[(size_t)p * (512 * 576) + r * 576 + c];
    c0[r * 64 + (c - 512)] = s;
  } else {
    bool direct = (c >> 6) >= 4 * (r >> 8);
    int rr = direct ? r : c, cc = direct ? c : r;
    for (int p = 0; p < nc; ++p) s += parts[(size_t)p * (512 * 576) + rr * 576 + cc];
    G[r * 512 + c] = s;
  }
}

// ---------------------------------------------------------------- apply_g
__global__ __launch_bounds__(256) void apply_g_kernel(
    const float* __restrict__ G, const float* __restrict__ filt,
    const float* __restrict__ cin, float* __restrict__ cout) {
  __shared__ float red[4][64];
  const int t = threadIdx.x;
  const int i = blockIdx.x;
  const int sub = t >> 6, d = t & 63;
  float s = 0.f;
#pragma unroll 8
  for (int j = sub * 128; j < (sub + 1) * 128; ++j)
    s += G[i * 512 + j] * (filt[j] * cin[j * 64 + d]);
  red[sub][d] = s;
  __syncthreads();
  if (sub == 0)
    cout[i * 64 + d] = red[0][d] + red[1][d] + red[2][d] + red[3][d];
}

// ---------------------------------------------------------------- prep_wt
// wsum = f0⊙c0 + f1⊙c1 + f2⊙c2; wt_h[d][f] = bf16_rne(wsum[f][d])
__global__ __launch_bounds__(256) void prep_wt_kernel(
    const float* __restrict__ filters, const float* __restrict__ c0,
    const float* __restrict__ c1, const float* __restrict__ c2,
    u16* __restrict__ wt_h) {
  int idx = blockIdx.x * 256 + threadIdx.x;  // 64*512
  int d = idx >> 9, f = idx & 511;
  float w = filters[f] * c0[f * 64 + d] + filters[512 + f] * c1[f * 64 + d] +
            filters[1024 + f] * c2[f * 64 + d];
  wt_h[d * FD + f] = bf16_rne(w);
}

// ---------------------------------------------------------------- expand
// out = (out + V @ wsum) * 0.25, pure bf16-h. R6-proven.
__global__ __launch_bounds__(256) void expand_kernel(
    const float* __restrict__ v, const u16* __restrict__ wt_h,
    float* __restrict__ out) {
  __shared__ float raw[2][128 * 64];
  const int t = threadIdx.x;
  const int lane = t & 63, wv = t >> 6;
  const int m16 = lane & 15, quad = lane >> 4;
  const int nb = blockIdx.x * 128;

  f32x4 acc[2][4];
#pragma unroll
  for (int a = 0; a < 2; ++a)
#pragma unroll
    for (int b = 0; b < 4; ++b) acc[a][b] = (f32x4){0.f, 0.f, 0.f, 0.f};

  auto stage = [&](int buf, int fs) {
#pragma unroll
    for (int g = 0; g < 8; ++g) {
      int rl = g * 4 + (lane >> 4);
      int sw = rl & 7;
      int grow = min(nb + wv * 32 + rl, N_TOTAL - 1);
      const float* gp = v + (size_t)grow * FD + fs + (((lane & 15) ^ sw) << 2);
      load_lds16(gp, &raw[buf][(wv * 32 + g * 4) * 64]);
    }
  };

  stage(0, 0);
  for (int it8 = 0; it8 < 8; ++it8) {
    const int buf = it8 & 1, fs = it8 * 64;
    short8 pbh[2][4];
#pragma unroll
    for (int k = 0; k < 2; ++k)
#pragma unroll
      for (int ct = 0; ct < 4; ++ct) {
        const size_t off = (size_t)(ct * 16 + m16) * FD + fs + k * 32 + quad * 8;
        pbh[k][ct] = *(const short8*)(wt_h + off);
      }
    asm volatile("" ::: "memory");  // pin wt loads before stage batch
    if (it8 + 1 < 8) {
      stage(buf ^ 1, fs + 64);
      asm volatile("s_waitcnt vmcnt(16)" ::: "memory");
    } else {
      asm volatile("s_waitcnt vmcnt(8)" ::: "memory");
    }
#pragma unroll
    for (int k0i = 0; k0i < 2; ++k0i) {
      short8 ah[2];
#pragma unroll
      for (int mt = 0; mt < 2; ++mt) {
        const float* rb = &raw[buf][(wv * 32 + mt * 16 + m16) * 64];
        const int sw = m16 & 7;
        const int j0 = k0i * 8 + quad * 2;
        f32x4 xa = *(const f32x4*)(rb + ((j0 ^ sw) << 2));
        f32x4 xb = *(const f32x4*)(rb + (((j0 + 1) ^ sw) << 2));
        U8x H;
        H.u[0] = pack_h(f32u(xa[0]), f32u(xa[1]));
        H.u[1] = pack_h(f32u(xa[2]), f32u(xa[3]));
        H.u[2] = pack_h(f32u(xb[0]), f32u(xb[1]));
        H.u[3] = pack_h(f32u(xb[2]), f32u(xb[3]));
        ah[mt] = H.s;
      }
#pragma unroll
      for (int ct = 0; ct < 4; ++ct)
#pragma unroll
        for (int mt = 0; mt < 2; ++mt)
          acc[mt][ct] = __builtin_amdgcn_mfma_f32_16x16x32_bf16(ah[mt], pbh[k0i][ct], acc[mt][ct], 0, 0, 0);
    }
  }

#pragma unroll
  for (int mt = 0; mt < 2; ++mt) {
    int nrow = nb + wv * 32 + mt * 16 + quad * 4;
#pragma unroll
    for (int ct = 0; ct < 4; ++ct) {
      int d = ct * 16 + m16;
#pragma unroll
      for (int reg = 0; reg < 4; ++reg) {
        int n = nrow + reg;
        if (n < N_TOTAL) {
          float* op = out + (size_t)n * DQ + d;
          *op = (*op + acc[mt][ct][reg]) * 0.25f;
        }
      }
    }
  }
}

// ---------------------------------------------------------------- launch
extern "C" void kernel_launch(void* const* d_in, const int* in_sizes, int n_in,
                              void* d_out, int out_size, void* d_ws, size_t ws_size,
                              hipStream_t stream) {
  const float* user_emb = (const float*)d_in[0];
  const float* item_emb = (const float*)d_in[1];
  const float* v        = (const float*)d_in[2];
  const float* filters  = (const float*)d_in[3];
  float* out = (float*)d_out;

  const size_t EGOTB_BYTES = (size_t)(NPAD / 32) * 8192;     // 18.2 MB
  const size_t VB_BYTES    = (size_t)NPAD * FD * 2;          // 72.8 MB each
  const size_t SMALL_BYTES = (512 * 512 + 3 * 512 * 64) * 4 + DQ * FD * 2;
  const size_t PART_BYTES  = (size_t)512 * 576 * 4;

  // fast path: pre-split V blobs + copy-staging gram (needs ~206 MB)
  size_t fixed_fast = EGOTB_BYTES + 2 * VB_BYTES + SMALL_BYTES;
  int nc_fast = ws_size > fixed_fast ? (int)((ws_size - fixed_fast) / PART_BYTES) : 0;
  const bool fast = (nc_fast >= 28);

  int nc;
  if (fast) {
    nc = nc_fast > 35 ? 35 : nc_fast;
  } else {
    size_t fixed = EGOTB_BYTES + SMALL_BYTES;
    size_t avail = ws_size > fixed ? ws_size - fixed : 0;
    nc = (int)(avail / PART_BYTES);
    if (nc > 35) nc = 35;
    if (nc < 1) nc = 1;
  }
  int chunk = ((NPAD + nc - 1) / nc + 31) & ~31;
  int ncA = (NPAD + chunk - 1) / chunk;

  char* p = (char*)d_ws;
  u16* egoTb = (u16*)p;            p += EGOTB_BYTES;
  u16* vbh = nullptr; u16* vbl = nullptr;
  if (fast) { vbh = (u16*)p; p += VB_BYTES; vbl = (u16*)p; p += VB_BYTES; }
  float* parts = (float*)p;        p += (size_t)ncA * PART_BYTES;
  float* G     = (float*)p;        p += (size_t)512 * 512 * 4;
  float* c0    = (float*)p;        p += (size_t)512 * 64 * 4;
  float* c1    = (float*)p;        p += (size_t)512 * 64 * 4;
  float* c2    = (float*)p;        p += (size_t)512 * 64 * 4;
  u16* wt_h    = (u16*)p;

  init_kernel<<<NPAD / 64, 256, 0, stream>>>(user_emb, item_emb, out, egoTb);
  if (fast) {
    presplit_kernel<<<NPAD / 64, 256, 0, stream>>>(v, vbh, vbl);
    gram_fast_kernel<<<dim3(14, ncA), 256, 0, stream>>>(vbh, vbl, egoTb, parts, chunk);
  } else {
    gram_split_kernel<<<dim3(14, ncA), 256, 0, stream>>>(v, egoTb, parts, chunk);
  }
  finalize_kernel<<<(512 * 576) / 256, 256, 0, stream>>>(parts, ncA, G, c0);
  apply_g_kernel<<<512, 256, 0, stream>>>(G, filters, c0, c1);
  apply_g_kernel<<<512, 256, 0, stream>>>(G, filters + 512, c1, c2);
  prep_wt_kernel<<<128, 256, 0, stream>>>(filters, c0, c1, c2, wt_h);
  expand_kernel<<<NPAD / 128, 256, 0, stream>>>(v, wt_h, out);
}

// Round 8
// 445.591 us; speedup vs baseline: 1.1469x; 1.1469x over previous
//
#include <hip/hip_runtime.h>
#include <hip/hip_bf16.h>

// LGCN_Encoder via Gram-matrix collapse.
//   G = V^T V (512x512, layer-invariant), c0 = V^T ego0
//   c_{k+1} = G (f_k ⊙ c_k)  [tiny]
//   out = (ego0 + V (w1+w2+w3))/4,  w_k = f_{k-1} ⊙ c_{k-1}
//
// R8 (from R7=511us): gram VALU fix worked (VALUBusy 35->9, gram 192->160)
// but h+l blobs = 4B/elem kept FETCH at 521MB and presplit's serial-barrier
// structure cost ~100us. This round:
//  - PURE-H gram (RNE): 1 MFMA per fragment, 2B/elem -> logical traffic
//    halves (1.02GB -> 0.56GB), LDS 40->20KB. Error budget: RNE unbiased,
//    sqrt(N)-cancel; predicted absmax ~4-5e11 < 8.85e11 threshold.
//  - presplit rebuilt: NO LDS, NO barriers, direct 64B-coalesced column
//    gather (16 lanes x 4B = one transaction), RNE, h-only output.
//  - nc 35->56 (ws proven >=198MB by R7 fast-path run; fixed cost now ~93MB)
//    -> 784 gram blocks ~= 3/CU residency cap.
//  - everything else verbatim proven (init, gram_split fallback, finalize,
//    apply, prep, expand pure-h).

#define N_USERS 29858
#define N_TOTAL 70839
#define DQ 64
#define FD 512
#define NPAD 71168   // 139*512

typedef __attribute__((ext_vector_type(8))) short short8;
typedef __attribute__((ext_vector_type(4))) float f32x4;
typedef unsigned int u32;
typedef unsigned short u16;

static __device__ __forceinline__ u32 f32u(float x){union{float f;u32 u;}a;a.f=x;return a.u;}
static __device__ __forceinline__ float uf32(u32 u){union{u32 u;float f;}a;a.u=u;return a.f;}
// pack high halves: (hi16(x1)<<16) | hi16(x0)
static __device__ __forceinline__ u32 pack_h(u32 x0, u32 x1){
  return __builtin_amdgcn_perm(x1, x0, 0x07060302u);
}
// trunc split of two f32 into bf16 h-pair and l-pair dwords
static __device__ __forceinline__ void split_pair(u32 x0, u32 x1, u32& hp, u32& lp) {
  hp = pack_h(x0, x1);
  u32 l0 = f32u(uf32(x0) - uf32(x0 & 0xFFFF0000u));
  u32 l1 = f32u(uf32(x1) - uf32(x1 & 0xFFFF0000u));
  lp = pack_h(l0, l1);
}
union U8x { u32 u[4]; short8 s; };

static __device__ __forceinline__ u16 bf16_rne(float x) {
  u32 u = f32u(x);
  return (u16)((u + 0x7FFFu + ((u >> 16) & 1u)) >> 16);
}
static __device__ __forceinline__ void split2(float x, u16& h, u16& l) {
  h = bf16_rne(x);
  l = bf16_rne(x - uf32(((u32)h) << 16));
}

static __device__ __forceinline__ void load_lds16(const float* g, float* l) {
  __builtin_amdgcn_global_load_lds(
      (const __attribute__((address_space(1))) u32*)(g),
      (__attribute__((address_space(3))) u32*)(l), 16, 0, 0);
}

// Blob layout (hardware-verified via egoTb / R3-Output0 / R7 gram_fast):
// tile T = (n>>5)*8 + (f>>6); slot s = (f'&15) + ((f'>>4)&3)*64 + ((n'>>3)&3)*16
// (f'=f&63, n'=n&31); slot holds 8 bf16, n ascending. Fragment (ct,m16,quad)
// reads slot m16 + ct*64 + quad*16; A-fragments use the same math.

// ---------------------------------------------------------------- init
// out = concat(user,item) (for expand's RMW); egoTb = ego0 pre-split blobs
// (h plane RNE, l plane trunc-residual; gram_fast_h uses h only).
__global__ __launch_bounds__(256) void init_kernel(
    const float* __restrict__ u, const float* __restrict__ it,
    float* __restrict__ out, u16* __restrict__ egoTb) {
  __shared__ float tile[64][65];
  const int n0 = blockIdx.x * 64;
  const int t = threadIdx.x;
  const int r = t >> 2, cbase = (t & 3) * 16;
  {
    int n = n0 + r;
    if (n < N_TOTAL) {
      const float* src = (n < N_USERS) ? (u + (size_t)n * DQ)
                                       : (it + (size_t)(n - N_USERS) * DQ);
#pragma unroll
      for (int q = 0; q < 4; ++q) {
        f32x4 val = *(const f32x4*)(src + cbase + q * 4);
        *(f32x4*)(out + (size_t)n * DQ + cbase + q * 4) = val;
        tile[r][cbase + q * 4 + 0] = val[0];
        tile[r][cbase + q * 4 + 1] = val[1];
        tile[r][cbase + q * 4 + 2] = val[2];
        tile[r][cbase + q * 4 + 3] = val[3];
      }
    } else {
#pragma unroll
      for (int q = 0; q < 4; ++q)
#pragma unroll
        for (int e = 0; e < 4; ++e) tile[r][cbase + q * 4 + e] = 0.f;
    }
  }
  __syncthreads();
  const int d = (t & 15) | ((t >> 6) << 4);
  const int nb = (t >> 4) & 3;
#pragma unroll
  for (int sl = 0; sl < 2; ++sl) {
    U8x H, L;
#pragma unroll
    for (int j = 0; j < 4; ++j) {
      u16 h0, l0, h1, l1;
      split2(tile[sl * 32 + nb * 8 + 2 * j][d], h0, l0);
      split2(tile[sl * 32 + nb * 8 + 2 * j + 1][d], h1, l1);
      H.u[j] = (u32)h0 | ((u32)h1 << 16);
      L.u[j] = (u32)l0 | ((u32)l1 << 16);
    }
    size_t base = (size_t)(blockIdx.x * 2 + sl) * 4096;  // u16 units
    *(short8*)(egoTb + base + (size_t)t * 8) = H.s;
    *(short8*)(egoTb + base + 2048 + (size_t)t * 8) = L.s;
  }
}

// ---------------------------------------------------------------- presplit
// V -> vbh blobs, RNE, h only. Pure streaming: no LDS, no barriers.
// Thread t = blob slot; gathers its 8 n-values per f-tile directly.
// Coalescing: 16 lanes (f' 0..15) x 4B = one 64B transaction per row-group;
// the 4 waves cover adjacent f' ranges completing each 128B line.
__global__ __launch_bounds__(256) void presplit_kernel(
    const float* __restrict__ v, u16* __restrict__ vbh) {
  const int n0 = blockIdx.x * 32;
  const int t = threadIdx.x;
  const int fp = (t & 15) | ((t >> 6) << 4);
  const int nb = (t >> 4) & 3;
  const int nbase = n0 + nb * 8;
  const size_t Tb = (size_t)(n0 >> 5) * 8;
  if (nbase + 8 <= N_TOTAL) {
#pragma unroll
    for (int tf = 0; tf < 8; ++tf) {
      const float* col = v + (size_t)nbase * FD + tf * 64 + fp;
      U8x H;
#pragma unroll
      for (int j = 0; j < 4; ++j) {
        u16 h0 = bf16_rne(col[(size_t)(2 * j) * FD]);
        u16 h1 = bf16_rne(col[(size_t)(2 * j + 1) * FD]);
        H.u[j] = (u32)h0 | ((u32)h1 << 16);
      }
      *(short8*)(vbh + (Tb + tf) * 2048 + (size_t)t * 8) = H.s;
    }
  } else {
#pragma unroll
    for (int tf = 0; tf < 8; ++tf) {
      U8x H;
#pragma unroll
      for (int j = 0; j < 4; ++j) {
        int na = nbase + 2 * j, nbv = nbase + 2 * j + 1;
        float xa = (na < N_TOTAL) ? v[(size_t)na * FD + tf * 64 + fp] : 0.f;
        float xb = (nbv < N_TOTAL) ? v[(size_t)nbv * FD + tf * 64 + fp] : 0.f;
        H.u[j] = (u32)bf16_rne(xa) | ((u32)bf16_rne(xb) << 16);
      }
      *(short8*)(vbh + (Tb + tf) * 2048 + (size_t)t * 8) = H.s;
    }
  }
}

// ---------------------------------------------------------------- gram_fast
// Pure-h: 1 MFMA per fragment. Staging = pure 16B-blob copy. Job decode,
// barrier structure, fragment reads, epilogue: verbatim the proven R7 gram.
__global__ __launch_bounds__(256, 3) void gram_fast_kernel(
    const u16* __restrict__ vbh, const u16* __restrict__ egoTb,
    float* __restrict__ parts, int chunk) {
  __shared__ short8 HAh[1024];   // 256 f x 4 n-blk, 16 KB
  __shared__ short8 HBh[256];    // 64 cols x 4 n-blk, 4 KB

  const int job = blockIdx.x;
  const int n0c = blockIdx.y * chunk;
  const int nend = min(n0c + chunk, NPAD);
  const bool isC0 = (job >= 12);
  const int itile = isC0 ? (job - 12) : (job < 8 ? 0 : 1);
  const int fA = itile * 256;
  const int jcol = isC0 ? 0 : (job < 8 ? job : job - 4);
  const int colbase = jcol * 64;
  const bool reuseB = !isC0 && (colbase >= fA) && (colbase + 64 <= fA + 256);
  const bool stageB = !isC0 && !reuseB;
  const int cb0q = reuseB ? ((colbase - fA) >> 6) : 0;

  const int t = threadIdx.x;
  const int lane = t & 63, wv = t >> 6;
  const int m16 = lane & 15, quad = lane >> 4;
  const int ftA = fA >> 6;

  f32x4 acc[4][4];
#pragma unroll
  for (int a = 0; a < 4; ++a)
#pragma unroll
    for (int b = 0; b < 4; ++b) acc[a][b] = (f32x4){0.f, 0.f, 0.f, 0.f};

  short8 xAh[4], xBh;

  auto issue = [&](int n0) {
    size_t Tb = (size_t)(n0 >> 5) * 8;
    if (isC0) {
      xBh = *(const short8*)(egoTb + (size_t)(n0 >> 5) * 4096 + (size_t)t * 8);
    } else if (stageB) {
      xBh = *(const short8*)(vbh + (Tb + (colbase >> 6)) * 2048 + (size_t)t * 8);
    }
#pragma unroll
    for (int seg = 0; seg < 4; ++seg)
      xAh[seg] = *(const short8*)(vbh + (Tb + ftA + seg) * 2048 + (size_t)t * 8);
  };

  issue(n0c);

  for (int n0 = n0c; n0 < nend; n0 += 32) {
    asm volatile("s_barrier" ::: "memory");  // prev step's LDS reads done

#pragma unroll
    for (int seg = 0; seg < 4; ++seg)
      HAh[seg * 256 + t] = xAh[seg];
    if (stageB || isC0)
      HBh[t] = xBh;

    // prefetch next step's blobs: stay in flight across barrier + MFMAs
    if (n0 + 32 < nend) issue(n0 + 32);

    asm volatile("s_waitcnt lgkmcnt(0)" ::: "memory");  // ds_writes visible
    asm volatile("s_barrier" ::: "memory");             // NOT vmcnt-drained

    short8 ah[4];
#pragma unroll
    for (int mt = 0; mt < 4; ++mt)
      ah[mt] = HAh[m16 + mt * 64 + wv * 256 + quad * 16];
#pragma unroll
    for (int ct = 0; ct < 4; ++ct) {
      short8 bh;
      if (reuseB) {
        bh = HAh[m16 + ct * 64 + cb0q * 256 + quad * 16];
      } else {
        bh = HBh[m16 + ct * 64 + quad * 16];
      }
#pragma unroll
      for (int mt = 0; mt < 4; ++mt)
        acc[mt][ct] = __builtin_amdgcn_mfma_f32_16x16x32_bf16(ah[mt], bh, acc[mt][ct], 0, 0, 0);
    }
  }

  float* pb = parts + (size_t)blockIdx.y * (512 * 576);
  const int cb = isC0 ? 512 : colbase;
#pragma unroll
  for (int mt = 0; mt < 4; ++mt) {
    int row = fA + wv * 64 + mt * 16 + quad * 4;
#pragma unroll
    for (int ct = 0; ct < 4; ++ct) {
      int col = cb + ct * 16 + m16;
#pragma unroll
      for (int reg = 0; reg < 4; ++reg)
        pb[(size_t)(row + reg) * 576 + col] = acc[mt][ct][reg];
    }
  }
}

// ---------------------------------------------------------------- gram_split
// R4-proven fallback (in-kernel f32 load + trunc-split), used when ws_size
// can't hold the vb blobs. Verbatim.
__global__ __launch_bounds__(256, 2) void gram_split_kernel(
    const float* __restrict__ v, const u16* __restrict__ egoTb,
    float* __restrict__ parts, int chunk) {
  __shared__ short8 HAh[1024];
  __shared__ short8 HAl[1024];
  __shared__ short8 HBh[256];
  __shared__ short8 HBl[256];

  const int job = blockIdx.x;
  const int n0c = blockIdx.y * chunk;
  const int nend = min(n0c + chunk, NPAD);
  const bool isC0 = (job >= 12);
  const int itile = isC0 ? (job - 12) : (job < 8 ? 0 : 1);
  const int fA = itile * 256;
  const int jcol = isC0 ? 0 : (job < 8 ? job : job - 4);
  const int colbase = jcol * 64;
  const bool reuseB = !isC0 && (colbase >= fA) && (colbase + 64 <= fA + 256);
  const bool stageB = !isC0 && !reuseB;
  const int cb0q = reuseB ? ((colbase - fA) >> 6) : 0;

  const int t = threadIdx.x;
  const int lane = t & 63, wv = t >> 6;
  const int m16 = lane & 15, quad = lane >> 4;
  const int fl = lane, nq = wv;

  f32x4 acc[4][4];
#pragma unroll
  for (int a = 0; a < 4; ++a)
#pragma unroll
    for (int b = 0; b < 4; ++b) acc[a][b] = (f32x4){0.f, 0.f, 0.f, 0.f};

  u32 xA[4][8];
  u32 xB[8];
  short8 xBh, xBl;

  auto issue = [&](int n0) {
    if (isC0) {
      xBh = *(const short8*)(egoTb + (size_t)(n0 >> 5) * 4096 + (size_t)t * 8);
      xBl = *(const short8*)(egoTb + (size_t)(n0 >> 5) * 4096 + 2048 + (size_t)t * 8);
    }
#pragma unroll
    for (int seg = 0; seg < 4; ++seg)
#pragma unroll
      for (int r = 0; r < 8; ++r) {
        int n = n0 + nq * 8 + r;
        xA[seg][r] = (n < N_TOTAL) ? f32u(v[(size_t)n * FD + fA + seg * 64 + fl]) : 0u;
      }
    if (stageB) {
#pragma unroll
      for (int r = 0; r < 8; ++r) {
        int n = n0 + nq * 8 + r;
        xB[r] = (n < N_TOTAL) ? f32u(v[(size_t)n * FD + colbase + fl]) : 0u;
      }
    }
  };

  issue(n0c);

  for (int n0 = n0c; n0 < nend; n0 += 32) {
    asm volatile("s_barrier" ::: "memory");

    const int uw = (fl & 15) + ((fl >> 4) & 3) * 64 + nq * 16;
#pragma unroll
    for (int seg = 0; seg < 4; ++seg) {
      U8x H, L;
#pragma unroll
      for (int p = 0; p < 4; ++p)
        split_pair(xA[seg][2 * p], xA[seg][2 * p + 1], H.u[p], L.u[p]);
      HAh[uw + seg * 256] = H.s;
      HAl[uw + seg * 256] = L.s;
    }
    if (stageB) {
      U8x H, L;
#pragma unroll
      for (int p = 0; p < 4; ++p)
        split_pair(xB[2 * p], xB[2 * p + 1], H.u[p], L.u[p]);
      HBh[uw] = H.s;
      HBl[uw] = L.s;
    } else if (isC0) {
      HBh[t] = xBh;
      HBl[t] = xBl;
    }

    if (n0 + 32 < nend) issue(n0 + 32);

    asm volatile("s_waitcnt lgkmcnt(0)" ::: "memory");
    asm volatile("s_barrier" ::: "memory");

    short8 ah[4], al[4];
#pragma unroll
    for (int mt = 0; mt < 4; ++mt) {
      int u = m16 + mt * 64 + wv * 256 + quad * 16;
      ah[mt] = HAh[u];
      al[mt] = HAl[u];
    }
#pragma unroll
    for (int ct = 0; ct < 4; ++ct) {
      short8 bh, bl;
      if (reuseB) {
        int u = m16 + ct * 64 + cb0q * 256 + quad * 16;
        bh = HAh[u]; bl = HAl[u];
      } else {
        int u = m16 + ct * 64 + quad * 16;
        bh = HBh[u]; bl = HBl[u];
      }
#pragma unroll
      for (int mt = 0; mt < 4; ++mt) {
        acc[mt][ct] = __builtin_amdgcn_mfma_f32_16x16x32_bf16(ah[mt], bh, acc[mt][ct], 0, 0, 0);
        acc[mt][ct] = __builtin_amdgcn_mfma_f32_16x16x32_bf16(ah[mt], bl, acc[mt][ct], 0, 0, 0);
        acc[mt][ct] = __builtin_amdgcn_mfma_f32_16x16x32_bf16(al[mt], bh, acc[mt][ct], 0, 0, 0);
      }
    }
  }

  float* pb = parts + (size_t)blockIdx.y * (512 * 576);
  const int cb = isC0 ? 512 : colbase;
#pragma unroll
  for (int mt = 0; mt < 4; ++mt) {
    int row = fA + wv * 64 + mt * 16 + quad * 4;
#pragma unroll
    for (int ct = 0; ct < 4; ++ct) {
      int col = cb + ct * 16 + m16;
#pragma unroll
      for (int reg = 0; reg < 4; ++reg)
        pb[(size_t)(row + reg) * 576 + col] = acc[mt][ct][reg];
    }
  }
}

// ---------------------------------------------------------------- finalize
__global__ __launch_bounds__(256) void finalize_kernel(
    const float* __restrict__ parts, int nc,
    float* __restrict__ G, float* __restrict__ c0) {
  int idx = blockIdx.x * 256 + threadIdx.x;  // 512*576
  int r = idx / 576, c = idx % 576;
  float s = 0.f;
  if (c >= 512) {
    for (int p = 0; p < nc; ++p) s += parts[(size_t)p * (512 * 576) + r * 576 + c];
    c0[r * 64 + (c - 512)] = s;
  } else {
    bool direct = (c >> 6) >= 4 * (r >> 8);
    int rr = direct ? r : c, cc = direct ? c : r;
    for (int p = 0; p < nc; ++p) s += parts[(size_t)p * (512 * 576) + rr * 576 + cc];
    G[r * 512 + c] = s;
  }
}

// ---------------------------------------------------------------- apply_g
__global__ __launch_bounds__(256) void apply_g_kernel(
    const float* __restrict__ G, const float* __restrict__ filt,
    const float* __restrict__ cin, float* __restrict__ cout) {
  __shared__ float red[4][64];
  const int t = threadIdx.x;
  const int i = blockIdx.x;
  const int sub = t >> 6, d = t & 63;
  float s = 0.f;
#pragma unroll 8
  for (int j = sub * 128; j < (sub + 1) * 128; ++j)
    s += G[i * 512 + j] * (filt[j] * cin[j * 64 + d]);
  red[sub][d] = s;
  __syncthreads();
  if (sub == 0)
    cout[i * 64 + d] = red[0][d] + red[1][d] + red[2][d] + red[3][d];
}

// ---------------------------------------------------------------- prep_wt
// wsum = f0⊙c0 + f1⊙c1 + f2⊙c2; wt_h[d][f] = bf16_rne(wsum[f][d])
__global__ __launch_bounds__(256) void prep_wt_kernel(
    const float* __restrict__ filters, const float* __restrict__ c0,
    const float* __restrict__ c1, const float* __restrict__ c2,
    u16* __restrict__ wt_h) {
  int idx = blockIdx.x * 256 + threadIdx.x;  // 64*512
  int d = idx >> 9, f = idx & 511;
  float w = filters[f] * c0[f * 64 + d] + filters[512 + f] * c1[f * 64 + d] +
            filters[1024 + f] * c2[f * 64 + d];
  wt_h[d * FD + f] = bf16_rne(w);
}

// ---------------------------------------------------------------- expand
// out = (out + V @ wsum) * 0.25, pure bf16-h. R6/R7-proven verbatim.
__global__ __launch_bounds__(256) void expand_kernel(
    const float* __restrict__ v, const u16* __restrict__ wt_h,
    float* __restrict__ out) {
  __shared__ float raw[2][128 * 64];
  const int t = threadIdx.x;
  const int lane = t & 63, wv = t >> 6;
  const int m16 = lane & 15, quad = lane >> 4;
  const int nb = blockIdx.x * 128;

  f32x4 acc[2][4];
#pragma unroll
  for (int a = 0; a < 2; ++a)
#pragma unroll
    for (int b = 0; b < 4; ++b) acc[a][b] = (f32x4){0.f, 0.f, 0.f, 0.f};

  auto stage = [&](int buf, int fs) {
#pragma unroll
    for (int g = 0; g < 8; ++g) {
      int rl = g * 4 + (lane >> 4);
      int sw = rl & 7;
      int grow = min(nb + wv * 32 + rl, N_TOTAL - 1);
      const float* gp = v + (size_t)grow * FD + fs + (((lane & 15) ^ sw) << 2);
      load_lds16(gp, &raw[buf][(wv * 32 + g * 4) * 64]);
    }
  };

  stage(0, 0);
  for (int it8 = 0; it8 < 8; ++it8) {
    const int buf = it8 & 1, fs = it8 * 64;
    short8 pbh[2][4];
#pragma unroll
    for (int k = 0; k < 2; ++k)
#pragma unroll
      for (int ct = 0; ct < 4; ++ct) {
        const size_t off = (size_t)(ct * 16 + m16) * FD + fs + k * 32 + quad * 8;
        pbh[k][ct] = *(const short8*)(wt_h + off);
      }
    asm volatile("" ::: "memory");  // pin wt loads before stage batch
    if (it8 + 1 < 8) {
      stage(buf ^ 1, fs + 64);
      asm volatile("s_waitcnt vmcnt(16)" ::: "memory");
    } else {
      asm volatile("s_waitcnt vmcnt(8)" ::: "memory");
    }
#pragma unroll
    for (int k0i = 0; k0i < 2; ++k0i) {
      short8 ah[2];
#pragma unroll
      for (int mt = 0; mt < 2; ++mt) {
        const float* rb = &raw[buf][(wv * 32 + mt * 16 + m16) * 64];
        const int sw = m16 & 7;
        const int j0 = k0i * 8 + quad * 2;
        f32x4 xa = *(const f32x4*)(rb + ((j0 ^ sw) << 2));
        f32x4 xb = *(const f32x4*)(rb + (((j0 + 1) ^ sw) << 2));
        U8x H;
        H.u[0] = pack_h(f32u(xa[0]), f32u(xa[1]));
        H.u[1] = pack_h(f32u(xa[2]), f32u(xa[3]));
        H.u[2] = pack_h(f32u(xb[0]), f32u(xb[1]));
        H.u[3] = pack_h(f32u(xb[2]), f32u(xb[3]));
        ah[mt] = H.s;
      }
#pragma unroll
      for (int ct = 0; ct < 4; ++ct)
#pragma unroll
        for (int mt = 0; mt < 2; ++mt)
          acc[mt][ct] = __builtin_amdgcn_mfma_f32_16x16x32_bf16(ah[mt], pbh[k0i][ct], acc[mt][ct], 0, 0, 0);
    }
  }

#pragma unroll
  for (int mt = 0; mt < 2; ++mt) {
    int nrow = nb + wv * 32 + mt * 16 + quad * 4;
#pragma unroll
    for (int ct = 0; ct < 4; ++ct) {
      int d = ct * 16 + m16;
#pragma unroll
      for (int reg = 0; reg < 4; ++reg) {
        int n = nrow + reg;
        if (n < N_TOTAL) {
          float* op = out + (size_t)n * DQ + d;
          *op = (*op + acc[mt][ct][reg]) * 0.25f;
        }
      }
    }
  }
}

// ---------------------------------------------------------------- launch
extern "C" void kernel_launch(void* const* d_in, const int* in_sizes, int n_in,
                              void* d_out, int out_size, void* d_ws, size_t ws_size,
                              hipStream_t stream) {
  const float* user_emb = (const float*)d_in[0];
  const float* item_emb = (const float*)d_in[1];
  const float* v        = (const float*)d_in[2];
  const float* filters  = (const float*)d_in[3];
  float* out = (float*)d_out;

  const size_t EGOTB_BYTES = (size_t)(NPAD / 32) * 8192;     // 18.2 MB
  const size_t VB_BYTES    = (size_t)NPAD * FD * 2;          // 72.9 MB (h only)
  const size_t SMALL_BYTES = (512 * 512 + 3 * 512 * 64) * 4 + DQ * FD * 2;
  const size_t PART_BYTES  = (size_t)512 * 576 * 4;

  // fast path: pre-split h blobs + pure-h gram (needs ~93MB + parts)
  size_t fixed_fast = EGOTB_BYTES + VB_BYTES + SMALL_BYTES;
  int nc_fast = ws_size > fixed_fast ? (int)((ws_size - fixed_fast) / PART_BYTES) : 0;
  const bool fast = (nc_fast >= 28);

  int nc;
  if (fast) {
    nc = nc_fast > 56 ? 56 : nc_fast;
  } else {
    size_t fixed = EGOTB_BYTES + SMALL_BYTES;
    size_t avail = ws_size > fixed ? ws_size - fixed : 0;
    nc = (int)(avail / PART_BYTES);
    if (nc > 35) nc = 35;
    if (nc < 1) nc = 1;
  }
  int chunk = ((NPAD + nc - 1) / nc + 31) & ~31;
  int ncA = (NPAD + chunk - 1) / chunk;

  char* p = (char*)d_ws;
  u16* egoTb = (u16*)p;            p += EGOTB_BYTES;
  u16* vbh = nullptr;
  if (fast) { vbh = (u16*)p; p += VB_BYTES; }
  float* parts = (float*)p;        p += (size_t)ncA * PART_BYTES;
  float* G     = (float*)p;        p += (size_t)512 * 512 * 4;
  float* c0    = (float*)p;        p += (size_t)512 * 64 * 4;
  float* c1    = (float*)p;        p += (size_t)512 * 64 * 4;
  float* c2    = (float*)p;        p += (size_t)512 * 64 * 4;
  u16* wt_h    = (u16*)p;

  init_kernel<<<NPAD / 64, 256, 0, stream>>>(user_emb, item_emb, out, egoTb);
  if (fast) {
    presplit_kernel<<<NPAD / 32, 256, 0, stream>>>(v, vbh);
    gram_fast_kernel<<<dim3(14, ncA), 256, 0, stream>>>(vbh, egoTb, parts, chunk);
  } else {
    gram_split_kernel<<<dim3(14, ncA), 256, 0, stream>>>(v, egoTb, parts, chunk);
  }
  finalize_kernel<<<(512 * 576) / 256, 256, 0, stream>>>(parts, ncA, G, c0);
  apply_g_kernel<<<512, 256, 0, stream>>>(G, filters, c0, c1);
  apply_g_kernel<<<512, 256, 0, stream>>>(G, filters + 512, c1, c2);
  prep_wt_kernel<<<128, 256, 0, stream>>>(filters, c0, c1, c2, wt_h);
  expand_kernel<<<NPAD / 128, 256, 0, stream>>>(v, wt_h, out);
}